// Round 5
// baseline (393.395 us; speedup 1.0000x reference)
//
#include <hip/hip_runtime.h>
#include <hip/hip_bf16.h>

// Problem constants (B=2, S=2048, DIM=1536, 12 heads x hd=128)
// Inputs fp32; OUTPUT fp32. Workspace ~94.8 MB (see kernel_launch).
#define SEQ    2048
#define TOK    4096          // B*S
#define DMODEL 1536
#define QKVROW 4608          // 3*DMODEL
#define HD     128
#define SCALE  0.08838834764831845f  // 1/sqrt(128)

#define NSPLIT 4
#define KRANGE (SEQ / NSPLIT)
#define NPAIR  12
#define ROWS_P (NPAIR * SEQ)
#define OPART_ELEMS ((size_t)ROWS_P * HD)

typedef __attribute__((ext_vector_type(8))) short short8;
typedef __attribute__((ext_vector_type(4))) short short4v;
typedef __attribute__((ext_vector_type(4))) float f32x4;

__device__ __forceinline__ float b2f(short s) {
    union { unsigned u; float f; } x;
    x.u = ((unsigned)(unsigned short)s) << 16;
    return x.f;
}
__device__ __forceinline__ short f2b(float f) {
    union { float f; unsigned u; } x; x.f = f;
    unsigned u = x.u;
    unsigned r = (u + 0x7fffu + ((u >> 16) & 1u)) >> 16;  // RNE
    return (short)r;
}

// async 16B global->LDS (m97 pattern). LDS dest: wave-uniform base + lane*16.
__device__ __forceinline__ void gld_lds16(const short* g, short* l) {
    __builtin_amdgcn_global_load_lds(
        (__attribute__((address_space(1))) void*)(g),
        (__attribute__((address_space(3))) void*)(l), 16, 0, 0);
}

// ---------------------------------------------------------------------------
// Fused prepass: x fp32->bf16, Wqkv/Wout fp32 -> transposed bf16.
// ---------------------------------------------------------------------------
#define CVT_BLOCKS  6144   // TOK*DMODEL / 1024
#define TQKV_BLOCKS 1728   // (QKVROW/64)*(DMODEL/64)
#define TOUT_BLOCKS 576    // (DMODEL/64)*(DMODEL/64)

__device__ __forceinline__ void transpose_tile(
    const float* __restrict__ W, short* __restrict__ WT,
    int K, int N, int k0, int n0, int t, short (*tile)[65])
{
    {
        int j  = t & 63;
        int i0 = (t >> 6) * 16;
        for (int ii = 0; ii < 16; ++ii)
            tile[i0 + ii][j] = f2b(W[(size_t)(k0 + i0 + ii) * N + n0 + j]);
    }
    __syncthreads();
    {
        int i  = t & 63;
        int j0 = (t >> 6) * 16;
        for (int jj = 0; jj < 16; ++jj)
            WT[(size_t)(n0 + j0 + jj) * K + k0 + i] = tile[i][j0 + jj];
    }
}

__global__ __launch_bounds__(256) void prepass_k(
    const float* __restrict__ x, const float* __restrict__ Wqkv,
    const float* __restrict__ Wout, short* __restrict__ xb,
    short* __restrict__ WqkvT, short* __restrict__ WoutT)
{
    __shared__ short tile[64][65];
    const int bid = blockIdx.x;
    const int t   = threadIdx.x;
    if (bid < CVT_BLOCKS) {
        int i = bid * 1024 + t * 4;
        float4 v = *(const float4*)(x + i);
        short4v b = { f2b(v.x), f2b(v.y), f2b(v.z), f2b(v.w) };
        *(short4v*)(xb + i) = b;
    } else if (bid < CVT_BLOCKS + TQKV_BLOCKS) {
        int tb = bid - CVT_BLOCKS;
        transpose_tile(Wqkv, WqkvT, DMODEL, QKVROW,
                       (tb / (QKVROW / 64)) * 64, (tb % (QKVROW / 64)) * 64, t, tile);
    } else {
        int tb = bid - (CVT_BLOCKS + TQKV_BLOCKS);
        transpose_tile(Wout, WoutT, DMODEL, DMODEL,
                       (tb / (DMODEL / 64)) * 64, (tb % (DMODEL / 64)) * 64, t, tile);
    }
}

// ---------------------------------------------------------------------------
// GEMM: 64x256 tile, BK=32, double-buffered LDS, COMPILER-SCHEDULED inner
// loop (m97 mechanism: no inner barriers, no asm waits -- hipcc emits counted
// lgkmcnt so ds_read overlaps MFMA within each wave).  One __syncthreads per
// K-tile (its vmcnt(0) drain is covered by a full tile of compute since the
// next tile's stage is issued at the top of the iteration).
//   C[M,N] = A[M,K] @ BT[N,K]^T + bias[N].
// 256 threads = 4 waves (1M x 4N); per-wave output 64x64; acc[4][4] f32x4.
// LDS 40 KiB (2 slots x (A 4 + B 16 subtiles) x 1KB) -> up to 4 blocks/CU;
// small blocks pack both grids well (GEMM1 1152 blocks, GEMM2 384 blocks --
// every CU busy, unlike the 192-block 128x256 config).
//
// FRAGMENT-ORDER LDS subtiles [lane][16B]: every ds_read_b128 is
// base + lane*16 -> conflict-free (verified 0 conflicts r1-r4);
// global_load_lds (wave-uniform LDS dest) takes the permutation on the
// GLOBAL address side (m173 pattern): subtile b holds rows b*16..b*16+15,
// lane l supplies row (l&15), k-cols (l>>4)*8..+8 -- exactly the
// mfma_f32_16x16x32_bf16 operand layout.
//
// Hazards: reads of slot s (tile kt) were staged in iteration kt-1 and
// drained by its __syncthreads (vmcnt(0)) -> RAW safe.  Stage into s^1 at
// iteration kt happens after the syncthreads that followed s^1's last
// readers (lgkmcnt(0) per wave before barrier) -> WAR safe.
// Tail: kt+1 clamped to NTK-1 (redundant restage, never read, benign).
// ---------------------------------------------------------------------------
template <bool OUT_BF16, int MT, int NT>
__global__ __launch_bounds__(256, 4) void gemm_db(
    const short* __restrict__ A, const short* __restrict__ BT,
    const float* __restrict__ bias, void* __restrict__ Cout,
    int N, int K)
{
    __shared__ short smem[20480];   // 40 KiB: A 2x4x512, B 2x16x512

    // --- XCD-chunked bijective grid map (m204) + 4-wide N-band supertile ---
    constexpr int NWG = MT * NT;
    constexpr int Q8  = NWG / 8, R8 = NWG % 8;
    constexpr int BW  = 4;
    constexpr int FULLB = NT / BW;
    constexpr int TB  = FULLB * MT * BW;
    constexpr int TW  = NT - FULLB * BW;
    const int orig = blockIdx.x;
    const int xcd  = orig & 7, idx = orig >> 3;
    const int wg   = (xcd < R8 ? xcd * (Q8 + 1) : R8 * (Q8 + 1) + (xcd - R8) * Q8) + idx;
    int mt, nt;
    if (TW == 0 || wg < TB) {
        int band = wg / (MT * BW);
        int rem  = wg % (MT * BW);
        mt = rem / BW;
        nt = band * BW + rem % BW;
    } else {
        constexpr int TWD = TW ? TW : 1;
        int rem = wg - TB;
        mt = rem / TWD;
        nt = FULLB * BW + rem % TWD;
    }
    const int bm0 = mt * 64;
    const int bn0 = nt * 256;

    const int t    = threadIdx.x;
    const int wave = t >> 6;          // 0..3 = N-position of this wave
    const int lane = t & 63;
    const int quad = lane >> 4;
    const int lo   = lane & 15;

    // LDS subtile bases (shorts).  A: slot s, subtile st in [0,4);
    // B: slot s, subtile st in [0,16).
    auto ldsA = [&](int s, int st) { return smem + (s * 4 + st) * 512; };
    auto ldsB = [&](int s, int st) { return smem + 4096 + (s * 16 + st) * 512; };

    // Per-thread global sources (fragment-order permutation on GLOBAL side).
    // Wave w stages A-subtile w and B-subtiles 4w..4w+3.
    const int rO = quad * 8;
    const short* gA0 = A  + (size_t)(bm0 + wave * 16 + lo) * K + rO;
    const short* gB0 = BT + (size_t)(bn0 + wave * 64 + lo) * K + rO;
    const int bstep = 16 * K;   // row stride between B-subtiles

    f32x4 acc[4][4];
#pragma unroll
    for (int i = 0; i < 4; ++i)
#pragma unroll
        for (int j = 0; j < 4; ++j)
            acc[i][j] = (f32x4){0.f, 0.f, 0.f, 0.f};

    const int NTK = K >> 5;   // K-tiles of 32 (K=1536 -> 48)

#define STG(S, KT)                                                         \
    do {                                                                   \
        gld_lds16(gA0 + (KT) * 32, ldsA((S), wave));                       \
        for (int j = 0; j < 4; ++j)                                        \
            gld_lds16(gB0 + j * bstep + (KT) * 32, ldsB((S), wave * 4 + j)); \
    } while (0)

    // Prologue: slot0 <- tile0.
    STG(0, 0);
    __syncthreads();

    short8 af[2], bf[4];
#pragma unroll 1
    for (int kt = 0; kt < NTK; ++kt) {
        const int s  = kt & 1;
        const int nk = min(kt + 1, NTK - 1);
        // Issue all frag reads + next-tile stage; compiler interleaves the
        // lgkm waits with the MFMAs (m97 mechanism).
#pragma unroll
        for (int ni = 0; ni < 4; ++ni)
            bf[ni] = *(const short8*)(ldsB(s, wave * 4 + ni) + lane * 8);
        af[0] = *(const short8*)(ldsA(s, 0) + lane * 8);
        af[1] = *(const short8*)(ldsA(s, 1) + lane * 8);
        STG(s ^ 1, nk);
#pragma unroll
        for (int mi = 0; mi < 2; ++mi)
#pragma unroll
            for (int ni = 0; ni < 4; ++ni)
                acc[mi][ni] = __builtin_amdgcn_mfma_f32_16x16x32_bf16(
                    af[mi], bf[ni], acc[mi][ni], 0, 0, 0);
        af[0] = *(const short8*)(ldsA(s, 2) + lane * 8);
        af[1] = *(const short8*)(ldsA(s, 3) + lane * 8);
#pragma unroll
        for (int mi = 0; mi < 2; ++mi)
#pragma unroll
            for (int ni = 0; ni < 4; ++ni)
                acc[2 + mi][ni] = __builtin_amdgcn_mfma_f32_16x16x32_bf16(
                    af[mi], bf[ni], acc[2 + mi][ni], 0, 0, 0);
        __syncthreads();
    }
#undef STG

    // Epilogue: C = acc + bias.  col = bn0+wave*64+ni*16+lo,
    // row = bm0+a*16+quad*4+r  (16x16x32 C/D layout).
#pragma unroll
    for (int ni = 0; ni < 4; ++ni) {
        int col  = bn0 + wave * 64 + ni * 16 + lo;
        float bv = bias[col];
#pragma unroll
        for (int a = 0; a < 4; ++a)
#pragma unroll
            for (int r = 0; r < 4; ++r) {
                int row   = bm0 + a * 16 + quad * 4 + r;
                float val = acc[a][ni][r] + bv;
                if (OUT_BF16)
                    ((short*)Cout)[(size_t)row * N + col] = f2b(val);
                else
                    ((float*)Cout)[(size_t)row * N + col] = val;
            }
    }
}

// ---------------------------------------------------------------------------
// Flash attention full heads, split-K x4, fixed-m=0 softmax.  (unchanged)
// ---------------------------------------------------------------------------
#define KSP 136
#define VTP 44
#define PLP 40

__global__ __launch_bounds__(256) void attn_full_split(
    const short* __restrict__ qkv, short* __restrict__ Opart,
    float* __restrict__ lsum)
{
    const int pair = blockIdx.y;
    const int b    = pair / 6;
    const int h    = pair % 6;
    const int q0   = blockIdx.x * 64;
    const int kz   = blockIdx.z;
    const int t    = threadIdx.x;
    const int wave = t >> 6;
    const int lane = t & 63;
    const int quad = lane >> 4;
    const int lo   = lane & 15;

    __shared__ short Ks[32 * KSP];
    __shared__ short Vr[32 * KSP];
    __shared__ short Vt[128 * VTP];
    __shared__ short Pl[4][16 * PLP];

    const short* base = qkv + (size_t)b * SEQ * QKVROW;

    short8 qf[4];
    {
        int qrow = q0 + wave * 16 + lo;
        const short* qp = base + (size_t)qrow * QKVROW + h * HD;
        for (int c = 0; c < 4; ++c)
            qf[c] = *(const short8*)(qp + c * 32 + quad * 8);
    }

    f32x4 o[8];
    for (int i = 0; i < 8; ++i) o[i] = (f32x4){0.f, 0.f, 0.f, 0.f};
    float lrow[4] = {0.f, 0.f, 0.f, 0.f};

    const int skey = t >> 3;
    const int sdc  = (t & 7) * 16;
    const int thd  = t & 127;
    const int tkc  = (t >> 7) * 16;

    const int kend = kz * KRANGE + KRANGE;
    for (int k0 = kz * KRANGE; k0 < kend; k0 += 32) {
        {
            const short* kro = base + (size_t)(k0 + skey) * QKVROW + DMODEL     + h * HD + sdc;
            const short* vro = base + (size_t)(k0 + skey) * QKVROW + 2 * DMODEL + h * HD + sdc;
            short8 ka = *(const short8*)kro;
            short8 kb = *(const short8*)(kro + 8);
            short8 va = *(const short8*)vro;
            short8 vb = *(const short8*)(vro + 8);
            *(short8*)(Ks + skey * KSP + sdc)     = ka;
            *(short8*)(Ks + skey * KSP + sdc + 8) = kb;
            *(short8*)(Vr + skey * KSP + sdc)     = va;
            *(short8*)(Vr + skey * KSP + sdc + 8) = vb;
        }
        __syncthreads();

        {
            short8 x0, x1;
            for (int j = 0; j < 8; ++j) x0[j] = Vr[(tkc + j) * KSP + thd];
            for (int j = 0; j < 8; ++j) x1[j] = Vr[(tkc + 8 + j) * KSP + thd];
            *(short8*)(Vt + thd * VTP + tkc)     = x0;
            *(short8*)(Vt + thd * VTP + tkc + 8) = x1;
        }

        f32x4 s[2];
        s[0] = (f32x4){0.f, 0.f, 0.f, 0.f};
        s[1] = (f32x4){0.f, 0.f, 0.f, 0.f};
        for (int g = 0; g < 2; ++g)
            for (int c = 0; c < 4; ++c) {
                short8 kf = *(const short8*)(Ks + (g * 16 + lo) * KSP + c * 32 + quad * 8);
                s[g] = __builtin_amdgcn_mfma_f32_16x16x32_bf16(qf[c], kf, s[g], 0, 0, 0);
            }

        for (int g = 0; g < 2; ++g)
            for (int r = 0; r < 4; ++r) {
                float p = __expf(s[g][r] * SCALE);
                lrow[r] += p;
                Pl[wave][(quad * 4 + r) * PLP + g * 16 + lo] = f2b(p);
            }
        __syncthreads();

        short8 pf = *(const short8*)(&Pl[wave][lo * PLP + quad * 8]);
        for (int ni = 0; ni < 8; ++ni) {
            short8 vf = *(const short8*)(Vt + (ni * 16 + lo) * VTP + quad * 8);
            o[ni] = __builtin_amdgcn_mfma_f32_16x16x32_bf16(pf, vf, o[ni], 0, 0, 0);
        }
    }

    for (int r = 0; r < 4; ++r)
        for (int off = 1; off < 16; off <<= 1)
            lrow[r] += __shfl_xor(lrow[r], off, 64);

    for (int ni = 0; ni < 8; ++ni)
        for (int r = 0; r < 4; ++r) {
            int grow = pair * SEQ + q0 + wave * 16 + quad * 4 + r;
            Opart[(size_t)kz * OPART_ELEMS + (size_t)grow * HD + ni * 16 + lo] =
                f2b(o[ni][r]);
        }
    if (lo == 0)
        for (int r = 0; r < 4; ++r) {
            int grow = pair * SEQ + q0 + wave * 16 + quad * 4 + r;
            lsum[kz * ROWS_P + grow] = lrow[r];
        }
}

// ---------------------------------------------------------------------------
// Local heads (h=6..9), banded-flash MFMA.  (unchanged)
// ---------------------------------------------------------------------------
__global__ __launch_bounds__(256) void attn_local_mfma(
    const short* __restrict__ qkv, short* __restrict__ att)
{
    const int pair = blockIdx.y;          // 0..7
    const int b    = pair >> 2;
    const int h    = 6 + (pair & 3);
    const int q0   = blockIdx.x * 64;
    const int t    = threadIdx.x;
    const int wave = t >> 6;
    const int lane = t & 63;
    const int quad = lane >> 4;
    const int lo   = lane & 15;

    __shared__ short Ks[32 * KSP];
    __shared__ short Vr[32 * KSP];
    __shared__ short Vt[128 * VTP];
    __shared__ short Pl[4][16 * PLP];

    const short* base = qkv + (size_t)b * SEQ * QKVROW;

    short8 qf[4];
    {
        int qrow = q0 + wave * 16 + lo;
        const short* qp = base + (size_t)qrow * QKVROW + h * HD;
        for (int c = 0; c < 4; ++c)
            qf[c] = *(const short8*)(qp + c * 32 + quad * 8);
    }

    f32x4 o[8];
    for (int i = 0; i < 8; ++i) o[i] = (f32x4){0.f, 0.f, 0.f, 0.f};
    float lrow[4] = {0.f, 0.f, 0.f, 0.f};

    const int skey = t >> 3;
    const int sdc  = (t & 7) * 16;
    const int thd  = t & 127;
    const int tkc  = (t >> 7) * 16;
    const int irow = q0 + wave * 16 + quad * 4;   // query row = irow + r

    const int ks = max(0, q0 - 32);
    const int ke = min(SEQ, q0 + 96);
    for (int k0 = ks; k0 < ke; k0 += 32) {
        {
            const short* kro = base + (size_t)(k0 + skey) * QKVROW + DMODEL     + h * HD + sdc;
            const short* vro = base + (size_t)(k0 + skey) * QKVROW + 2 * DMODEL + h * HD + sdc;
            short8 ka = *(const short8*)kro;
            short8 kb = *(const short8*)(kro + 8);
            short8 va = *(const short8*)vro;
            short8 vb = *(const short8*)(vro + 8);
            *(short8*)(Ks + skey * KSP + sdc)     = ka;
            *(short8*)(Ks + skey * KSP + sdc + 8) = kb;
            *(short8*)(Vr + skey * KSP + sdc)     = va;
            *(short8*)(Vr + skey * KSP + sdc + 8) = vb;
        }
        __syncthreads();   // B1

        {
            short8 x0, x1;
            for (int j = 0; j < 8; ++j) x0[j] = Vr[(tkc + j) * KSP + thd];
            for (int j = 0; j < 8; ++j) x1[j] = Vr[(tkc + 8 + j) * KSP + thd];
            *(short8*)(Vt + thd * VTP + tkc)     = x0;
            *(short8*)(Vt + thd * VTP + tkc + 8) = x1;
        }

        f32x4 s[2];
        s[0] = (f32x4){0.f, 0.f, 0.f, 0.f};
        s[1] = (f32x4){0.f, 0.f, 0.f, 0.f};
        for (int g = 0; g < 2; ++g)
            for (int c = 0; c < 4; ++c) {
                short8 kf = *(const short8*)(Ks + (g * 16 + lo) * KSP + c * 32 + quad * 8);
                s[g] = __builtin_amdgcn_mfma_f32_16x16x32_bf16(qf[c], kf, s[g], 0, 0, 0);
            }

        // mask |i-j|<=32, p=exp(s*scale) else 0
        for (int g = 0; g < 2; ++g)
            for (int r = 0; r < 4; ++r) {
                int j = k0 + g * 16 + lo;
                int d = irow + r - j;
                float p = (d >= -32 && d <= 32) ? __expf(s[g][r] * SCALE) : 0.f;
                lrow[r] += p;
                Pl[wave][(quad * 4 + r) * PLP + g * 16 + lo] = f2b(p);
            }
        __syncthreads();   // B2

        short8 pf = *(const short8*)(&Pl[wave][lo * PLP + quad * 8]);
        for (int ni = 0; ni < 8; ++ni) {
            short8 vf = *(const short8*)(Vt + (ni * 16 + lo) * VTP + quad * 8);
            o[ni] = __builtin_amdgcn_mfma_f32_16x16x32_bf16(pf, vf, o[ni], 0, 0, 0);
        }
    }

    for (int r = 0; r < 4; ++r)
        for (int off = 1; off < 16; off <<= 1)
            lrow[r] += __shfl_xor(lrow[r], off, 64);

    for (int ni = 0; ni < 8; ++ni)
        for (int r = 0; r < 4; ++r) {
            int row = irow + r;
            size_t off = ((size_t)(b * SEQ + row)) * DMODEL + h * HD + ni * 16 + lo;
            att[off] = f2b(o[ni][r] / lrow[r]);
        }
}

// ---------------------------------------------------------------------------
// Fused post-attention: merge (heads 0-5) + global (10-11).  (unchanged)
// ---------------------------------------------------------------------------
#define MERGE_BLOCKS  12288   // NPAIR*SEQ*HD/256
#define GLOBAL_BLOCKS 2048    // (SEQ/4)*4

__global__ __launch_bounds__(256) void postattn_k(
    const short* __restrict__ qkv, const short* __restrict__ Opart,
    const float* __restrict__ lsum, short* __restrict__ att)
{
    const int bid  = blockIdx.x;
    const int t    = threadIdx.x;
    const int wave = t >> 6;
    const int lane = t & 63;

    if (bid < MERGE_BLOCKS) {
        int idx  = bid * 256 + t;
        int pair = idx >> 18;
        int q    = (idx >> 7) & (SEQ - 1);
        int hd   = idx & (HD - 1);
        int row  = pair * SEQ + q;
        float osum = 0.f, ls = 0.f;
        for (int z = 0; z < NSPLIT; ++z) {
            ls   += lsum[z * ROWS_P + row];
            osum += b2f(Opart[(size_t)z * OPART_ELEMS + (size_t)row * HD + hd]);
        }
        int b = pair / 6, h = pair % 6;
        att[((size_t)(b * SEQ + q)) * DMODEL + h * HD + hd] = f2b(osum / ls);
    } else {
        int gb   = bid - MERGE_BLOCKS;
        int pair = gb >> 9;               // 0..3
        int q    = (gb & 511) * 4 + wave;
        int b    = pair >> 1;
        int h    = 10 + (pair & 1);

        const short* base = qkv + (size_t)b * SEQ * QKVROW;
        const short* qp   = base + (size_t)q * QKVROW + h * HD;
        const short* k0   = base + DMODEL + h * HD;
        const short* k1   = base + (size_t)(SEQ - 1) * QKVROW + DMODEL + h * HD;

        float s0 = fmaf(b2f(qp[lane]), b2f(k0[lane]),
                   b2f(qp[lane + 64]) * b2f(k0[lane + 64]));
        float s1 = fmaf(b2f(qp[lane]), b2f(k1[lane]),
                   b2f(qp[lane + 64]) * b2f(k1[lane + 64]));
        for (int off = 1; off < 64; off <<= 1) {
            s0 += __shfl_xor(s0, off, 64);
            s1 += __shfl_xor(s1, off, 64);
        }
        s0 *= SCALE; s1 *= SCALE;
        float m  = fmaxf(s0, s1);
        float e0 = __expf(s0 - m), e1 = __expf(s1 - m);
        float inv = 1.f / (e0 + e1);
        float p0 = e0 * inv, p1 = e1 * inv;

        const short* v0 = base + 2 * DMODEL + h * HD;
        const short* v1 = base + (size_t)(SEQ - 1) * QKVROW + 2 * DMODEL + h * HD;
        size_t ob = ((size_t)(b * SEQ + q)) * DMODEL + h * HD;
        att[ob + lane]      = f2b(fmaf(p0, b2f(v0[lane]),      p1 * b2f(v1[lane])));
        att[ob + lane + 64] = f2b(fmaf(p0, b2f(v0[lane + 64]), p1 * b2f(v1[lane + 64])));
    }
}

// ---------------------------------------------------------------------------
extern "C" void kernel_launch(void* const* d_in, const int* in_sizes, int n_in,
                              void* d_out, int out_size, void* d_ws, size_t ws_size,
                              hipStream_t stream) {
    const float* x    = (const float*)d_in[0];
    const float* Wqkv = (const float*)d_in[1];
    const float* bqkv = (const float*)d_in[2];
    const float* Wout = (const float*)d_in[3];
    const float* bout = (const float*)d_in[4];

    // ws layout (~94.8 MB): att aliases xb (xb dead after GEMM1).
    char* p = (char*)d_ws;
    short* qkv   = (short*)p;  p += (size_t)TOK * QKVROW * 2;      // 37.75 MB
    short* Opart = (short*)p;  p += OPART_ELEMS * NSPLIT * 2;      // 25.17 MB
    float* lsum  = (float*)p;  p += (size_t)ROWS_P * NSPLIT * 4;   // 0.39 MB
    short* xb    = (short*)p;  p += (size_t)TOK * DMODEL * 2;      // 12.58 MB
    short* att   = xb;                                             // alias
    short* WqkvT = (short*)p;  p += (size_t)QKVROW * DMODEL * 2;   // 14.16 MB
    short* WoutT = (short*)p;                                      // 4.72 MB

    // 0) fused prepass
    prepass_k<<<dim3(CVT_BLOCKS + TQKV_BLOCKS + TOUT_BLOCKS), 256, 0, stream>>>(
        x, Wqkv, Wout, xb, WqkvT, WoutT);
    // 1) QKV = x @ Wqkv + bqkv (bf16 out): 64x256 dbuf, 1152 blocks
    gemm_db<true, 64, 18><<<dim3(64 * 18), 256, 0, stream>>>(
        xb, WqkvT, bqkv, (void*)qkv, QKVROW, DMODEL);
    // 2) attention: full split-K + banded local MFMA + fused merge/global
    attn_full_split<<<dim3(SEQ / 64, NPAIR, NSPLIT), 256, 0, stream>>>(qkv, Opart, lsum);
    attn_local_mfma<<<dim3(SEQ / 64, 8), 256, 0, stream>>>(qkv, att);
    postattn_k<<<dim3(MERGE_BLOCKS + GLOBAL_BLOCKS), 256, 0, stream>>>(
        qkv, Opart, lsum, att);
    // 3) out = att @ Wout + bout (fp32 out): 64x256 dbuf, 384 blocks
    gemm_db<false, 64, 6><<<dim3(64 * 6), 256, 0, stream>>>(
        att, WoutT, bout, d_out, DMODEL, DMODEL);
}

// Round 6
// 337.116 us; speedup vs baseline: 1.1669x; 1.1669x over previous
//
#include <hip/hip_runtime.h>
#include <hip/hip_bf16.h>

// Problem constants (B=2, S=2048, DIM=1536, 12 heads x hd=128)
// Inputs fp32; OUTPUT fp32. Workspace ~94.8 MB (see kernel_launch).
#define SEQ    2048
#define TOK    4096          // B*S
#define DMODEL 1536
#define QKVROW 4608          // 3*DMODEL
#define HD     128
#define SCALE  0.08838834764831845f  // 1/sqrt(128)

#define NSPLIT 4
#define KRANGE (SEQ / NSPLIT)
#define NPAIR  12
#define ROWS_P (NPAIR * SEQ)
#define OPART_ELEMS ((size_t)ROWS_P * HD)

typedef __attribute__((ext_vector_type(8))) short short8;
typedef __attribute__((ext_vector_type(4))) short short4v;
typedef __attribute__((ext_vector_type(4))) float f32x4;

__device__ __forceinline__ float b2f(short s) {
    union { unsigned u; float f; } x;
    x.u = ((unsigned)(unsigned short)s) << 16;
    return x.f;
}
__device__ __forceinline__ short f2b(float f) {
    union { float f; unsigned u; } x; x.f = f;
    unsigned u = x.u;
    unsigned r = (u + 0x7fffu + ((u >> 16) & 1u)) >> 16;  // RNE
    return (short)r;
}

// async 16B global->LDS (m97 pattern). LDS dest: wave-uniform base + lane*16.
__device__ __forceinline__ void gld_lds16(const short* g, short* l) {
    __builtin_amdgcn_global_load_lds(
        (__attribute__((address_space(1))) void*)(g),
        (__attribute__((address_space(3))) void*)(l), 16, 0, 0);
}

// ---------------------------------------------------------------------------
// Fused prepass: x fp32->bf16, Wqkv/Wout fp32 -> transposed bf16.
// ---------------------------------------------------------------------------
#define CVT_BLOCKS  6144   // TOK*DMODEL / 1024
#define TQKV_BLOCKS 1728   // (QKVROW/64)*(DMODEL/64)
#define TOUT_BLOCKS 576    // (DMODEL/64)*(DMODEL/64)

__device__ __forceinline__ void transpose_tile(
    const float* __restrict__ W, short* __restrict__ WT,
    int K, int N, int k0, int n0, int t, short (*tile)[65])
{
    {
        int j  = t & 63;
        int i0 = (t >> 6) * 16;
        for (int ii = 0; ii < 16; ++ii)
            tile[i0 + ii][j] = f2b(W[(size_t)(k0 + i0 + ii) * N + n0 + j]);
    }
    __syncthreads();
    {
        int i  = t & 63;
        int j0 = (t >> 6) * 16;
        for (int jj = 0; jj < 16; ++jj)
            WT[(size_t)(n0 + j0 + jj) * K + k0 + i] = tile[i][j0 + jj];
    }
}

__global__ __launch_bounds__(256) void prepass_k(
    const float* __restrict__ x, const float* __restrict__ Wqkv,
    const float* __restrict__ Wout, short* __restrict__ xb,
    short* __restrict__ WqkvT, short* __restrict__ WoutT)
{
    __shared__ short tile[64][65];
    const int bid = blockIdx.x;
    const int t   = threadIdx.x;
    if (bid < CVT_BLOCKS) {
        int i = bid * 1024 + t * 4;
        float4 v = *(const float4*)(x + i);
        short4v b = { f2b(v.x), f2b(v.y), f2b(v.z), f2b(v.w) };
        *(short4v*)(xb + i) = b;
    } else if (bid < CVT_BLOCKS + TQKV_BLOCKS) {
        int tb = bid - CVT_BLOCKS;
        transpose_tile(Wqkv, WqkvT, DMODEL, QKVROW,
                       (tb / (QKVROW / 64)) * 64, (tb % (QKVROW / 64)) * 64, t, tile);
    } else {
        int tb = bid - (CVT_BLOCKS + TQKV_BLOCKS);
        transpose_tile(Wout, WoutT, DMODEL, DMODEL,
                       (tb / (DMODEL / 64)) * 64, (tb % (DMODEL / 64)) * 64, t, tile);
    }
}

// ---------------------------------------------------------------------------
// GEMM: 128x256 tile, BK=32, 4-slot LDS pipeline (96 KiB), REGISTER
// READ-AHEAD one phase deep (the m201 mechanism the previous rounds lacked):
// the ds_reads for phase P+1 are issued during phase P, so the pre-MFMA
// lgkm wait targets reads issued a full phase earlier -> the 8-wave LDS
// convoy overlaps the MFMA convoy instead of serializing with it.
//   C[M,N] = A[M,K] @ BT[N,K]^T + bias[N].
// 512 threads = 8 waves (2M x 4N); per-wave output 64x64; acc[4][4] f32x4.
//
// FRAGMENT-ORDER LDS subtiles [lane][16B] (verified 0 conflicts r1-r5):
// ds_read_b128 = base + lane*16; global_load_lds takes the permutation on
// the GLOBAL address side (m173).  Slot = one BK=32 K-tile (A 8KB + B 16KB).
//
// Schedule (2 phases per tile; tile t lives in slot t&3):
//   phase A(t): read af_G1(t) | STAGE slot (t+3)&3 <- tile t+3 (3 glds/thr)
//               | MFMA G0 (regs from t-1 phase B) | vmcnt(6) | barrier
//   phase B(t): read bf(t+1), af_G0(t+1)          | MFMA G1  | barrier
// vmcnt(6) keeps the newest 2 tiles (6 loads) in flight -> tile t+1 landed
// before phase B reads it; tile t+3 has 6 phases (~3000 cyc >> 900-cyc HBM
// latency) to land.  Loads NEVER drain to 0 in the loop (T4).
// WAR: stage into slot (t+3)&3 = slot of tile t-1; its last readers'
// MFMAs lgkm-consumed before the end-of-(t-1)B barrier, 2 barriers before
// the stage issues.  Tail: tile indices clamped to NTK-1 (redundant
// restage/reads land in already-consumed slots, never read again).
// Even/odd register sets keep all frag indexing static (rule #20).
// ---------------------------------------------------------------------------
#define STG(SL, KT)                                                        \
    do {                                                                   \
        gld_lds16(gA0 + (KT) * 32, smem + (SL) * 12288 + wave * 512);      \
        gld_lds16(gB0 + (KT) * 32, smem + (SL) * 12288 + 4096 + wave * 512); \
        gld_lds16(gB1 + (KT) * 32, smem + (SL) * 12288 + 4096 + (8 + wave) * 512); \
    } while (0)
#define RD_A(DST, SL, G)                                                   \
    do {                                                                   \
        DST[0] = *(const short8*)(smem + (SL) * 12288 + (wm4 + (G) * 2) * 512 + lane * 8); \
        DST[1] = *(const short8*)(smem + (SL) * 12288 + (wm4 + (G) * 2 + 1) * 512 + lane * 8); \
    } while (0)
#define RD_B(DST, SL)                                                      \
    do {                                                                   \
        DST[0] = *(const short8*)(smem + (SL) * 12288 + 4096 + (wn4 + 0) * 512 + lane * 8); \
        DST[1] = *(const short8*)(smem + (SL) * 12288 + 4096 + (wn4 + 1) * 512 + lane * 8); \
        DST[2] = *(const short8*)(smem + (SL) * 12288 + 4096 + (wn4 + 2) * 512 + lane * 8); \
        DST[3] = *(const short8*)(smem + (SL) * 12288 + 4096 + (wn4 + 3) * 512 + lane * 8); \
    } while (0)
#define MFMA_G(G, AF, BF)                                                  \
    do {                                                                   \
        __builtin_amdgcn_s_setprio(1);                                     \
        for (int mi = 0; mi < 2; ++mi)                                     \
            for (int ni = 0; ni < 4; ++ni)                                 \
                acc[(G) * 2 + mi][ni] = __builtin_amdgcn_mfma_f32_16x16x32_bf16( \
                    AF[mi], BF[ni], acc[(G) * 2 + mi][ni], 0, 0, 0);       \
        __builtin_amdgcn_s_setprio(0);                                     \
    } while (0)
#define BAR                                                                \
    do {                                                                   \
        asm volatile("" ::: "memory");                                     \
        __builtin_amdgcn_s_barrier();                                      \
        asm volatile("" ::: "memory");                                     \
    } while (0)
#define VMW asm volatile("s_waitcnt vmcnt(6)" ::: "memory")

template <bool OUT_BF16, int MT, int NT>
__global__ __launch_bounds__(512, 2) void gemm_p4(
    const short* __restrict__ A, const short* __restrict__ BT,
    const float* __restrict__ bias, void* __restrict__ Cout,
    int N, int K)
{
    __shared__ short smem[49152];   // 96 KiB: 4 slots x (A 8KB + B 16KB)

    // --- XCD-chunked bijective grid map (m204) + 4-wide N-band supertile ---
    constexpr int NWG = MT * NT;
    constexpr int Q8  = NWG / 8, R8 = NWG % 8;
    constexpr int BW  = 4;
    constexpr int FULLB = NT / BW;
    constexpr int TB  = FULLB * MT * BW;
    constexpr int TW  = NT - FULLB * BW;
    const int orig = blockIdx.x;
    const int xcd  = orig & 7, idx = orig >> 3;
    const int wg   = (xcd < R8 ? xcd * (Q8 + 1) : R8 * (Q8 + 1) + (xcd - R8) * Q8) + idx;
    int mt, nt;
    if (TW == 0 || wg < TB) {
        int band = wg / (MT * BW);
        int rem  = wg % (MT * BW);
        mt = rem / BW;
        nt = band * BW + rem % BW;
    } else {
        constexpr int TWD = TW ? TW : 1;
        int rem = wg - TB;
        mt = rem / TWD;
        nt = FULLB * BW + rem % TWD;
    }
    const int bm0 = mt * 128;
    const int bn0 = nt * 256;

    const int t    = threadIdx.x;
    const int wave = t >> 6;
    const int lane = t & 63;
    const int quad = lane >> 4;
    const int lo   = lane & 15;
    const int wm   = wave >> 2;        // 0..1  (M)
    const int wn   = wave & 3;         // 0..3  (N)
    const int wm4  = wm * 4;
    const int wn4  = wn * 4;

    // Per-thread global sources (fragment-order permutation on GLOBAL side;
    // LDS dest stays linear).  Wave w stages A-subtile w, B-subtiles w, w+8.
    const int rO = quad * 8;
    const short* gA0 = A  + (size_t)(bm0 + wave * 16 + lo) * K + rO;
    const short* gB0 = BT + (size_t)(bn0 + wave * 16 + lo) * K + rO;
    const short* gB1 = BT + (size_t)(bn0 + (8 + wave) * 16 + lo) * K + rO;

    f32x4 acc[4][4];
#pragma unroll
    for (int i = 0; i < 4; ++i)
#pragma unroll
        for (int j = 0; j < 4; ++j)
            acc[i][j] = (f32x4){0.f, 0.f, 0.f, 0.f};

    const int NTK = K >> 5;   // K-tiles of 32 (K=1536 -> 48, even)

    // Prologue: stage tiles 0,1,2 into slots 0,1,2; tile0 landed after
    // vmcnt(6) (keeps tiles 1,2); then pre-read tile0's G0 fragments.
    STG(0, 0); STG(1, 1); STG(2, 2);
    VMW;
    BAR;

    short8 a0[2], b0[4], n0[2], a1[2], b1[4], n1[2];
    RD_B(b0, 0); RD_A(a0, 0, 0);

#pragma unroll 1
    for (int it = 0; it < (NTK >> 1); ++it) {
        const int t0  = it * 2, t1 = t0 + 1;
        const int sl0 = t0 & 3, sl1 = t1 & 3;
        const int s3  = (t0 + 3) & 3, s4 = (t1 + 3) & 3;
        const int k3  = min(t0 + 3, NTK - 1), k4 = min(t1 + 3, NTK - 1);
        const int i2  = min(t0 + 2, NTK - 1), s2 = i2 & 3;
        // tile t0, phase A
        RD_A(n0, sl0, 1);
        STG(s3, k3);
        MFMA_G(0, a0, b0);
        VMW; BAR;
        // tile t0, phase B  (read-ahead tile t1's G0 frags)
        RD_B(b1, sl1); RD_A(a1, sl1, 0);
        MFMA_G(1, n0, b0);
        BAR;
        // tile t1, phase A
        RD_A(n1, sl1, 1);
        STG(s4, k4);
        MFMA_G(0, a1, b1);
        VMW; BAR;
        // tile t1, phase B  (read-ahead tile t0+2's G0 frags)
        RD_B(b0, s2); RD_A(a0, s2, 0);
        MFMA_G(1, n1, b1);
        BAR;
    }
    asm volatile("s_waitcnt vmcnt(0)" ::: "memory");

    // Epilogue: C = acc + bias.  col = bn0+wn*64+ni*16+lo,
    // row = bm0+wm*64+a*16+quad*4+r  (16x16x32 C/D layout).
#pragma unroll
    for (int ni = 0; ni < 4; ++ni) {
        int col  = bn0 + wn * 64 + ni * 16 + lo;
        float bv = bias[col];
#pragma unroll
        for (int a = 0; a < 4; ++a)
#pragma unroll
            for (int r = 0; r < 4; ++r) {
                int row   = bm0 + wm * 64 + a * 16 + quad * 4 + r;
                float val = acc[a][ni][r] + bv;
                if (OUT_BF16)
                    ((short*)Cout)[(size_t)row * N + col] = f2b(val);
                else
                    ((float*)Cout)[(size_t)row * N + col] = val;
            }
    }
}
#undef STG
#undef RD_A
#undef RD_B
#undef MFMA_G
#undef BAR
#undef VMW

// ---------------------------------------------------------------------------
// Flash attention full heads, split-K x4, fixed-m=0 softmax.  (unchanged)
// ---------------------------------------------------------------------------
#define KSP 136
#define VTP 44
#define PLP 40

__global__ __launch_bounds__(256) void attn_full_split(
    const short* __restrict__ qkv, short* __restrict__ Opart,
    float* __restrict__ lsum)
{
    const int pair = blockIdx.y;
    const int b    = pair / 6;
    const int h    = pair % 6;
    const int q0   = blockIdx.x * 64;
    const int kz   = blockIdx.z;
    const int t    = threadIdx.x;
    const int wave = t >> 6;
    const int lane = t & 63;
    const int quad = lane >> 4;
    const int lo   = lane & 15;

    __shared__ short Ks[32 * KSP];
    __shared__ short Vr[32 * KSP];
    __shared__ short Vt[128 * VTP];
    __shared__ short Pl[4][16 * PLP];

    const short* base = qkv + (size_t)b * SEQ * QKVROW;

    short8 qf[4];
    {
        int qrow = q0 + wave * 16 + lo;
        const short* qp = base + (size_t)qrow * QKVROW + h * HD;
        for (int c = 0; c < 4; ++c)
            qf[c] = *(const short8*)(qp + c * 32 + quad * 8);
    }

    f32x4 o[8];
    for (int i = 0; i < 8; ++i) o[i] = (f32x4){0.f, 0.f, 0.f, 0.f};
    float lrow[4] = {0.f, 0.f, 0.f, 0.f};

    const int skey = t >> 3;
    const int sdc  = (t & 7) * 16;
    const int thd  = t & 127;
    const int tkc  = (t >> 7) * 16;

    const int kend = kz * KRANGE + KRANGE;
    for (int k0 = kz * KRANGE; k0 < kend; k0 += 32) {
        {
            const short* kro = base + (size_t)(k0 + skey) * QKVROW + DMODEL     + h * HD + sdc;
            const short* vro = base + (size_t)(k0 + skey) * QKVROW + 2 * DMODEL + h * HD + sdc;
            short8 ka = *(const short8*)kro;
            short8 kb = *(const short8*)(kro + 8);
            short8 va = *(const short8*)vro;
            short8 vb = *(const short8*)(vro + 8);
            *(short8*)(Ks + skey * KSP + sdc)     = ka;
            *(short8*)(Ks + skey * KSP + sdc + 8) = kb;
            *(short8*)(Vr + skey * KSP + sdc)     = va;
            *(short8*)(Vr + skey * KSP + sdc + 8) = vb;
        }
        __syncthreads();

        {
            short8 x0, x1;
            for (int j = 0; j < 8; ++j) x0[j] = Vr[(tkc + j) * KSP + thd];
            for (int j = 0; j < 8; ++j) x1[j] = Vr[(tkc + 8 + j) * KSP + thd];
            *(short8*)(Vt + thd * VTP + tkc)     = x0;
            *(short8*)(Vt + thd * VTP + tkc + 8) = x1;
        }

        f32x4 s[2];
        s[0] = (f32x4){0.f, 0.f, 0.f, 0.f};
        s[1] = (f32x4){0.f, 0.f, 0.f, 0.f};
        for (int g = 0; g < 2; ++g)
            for (int c = 0; c < 4; ++c) {
                short8 kf = *(const short8*)(Ks + (g * 16 + lo) * KSP + c * 32 + quad * 8);
                s[g] = __builtin_amdgcn_mfma_f32_16x16x32_bf16(qf[c], kf, s[g], 0, 0, 0);
            }

        for (int g = 0; g < 2; ++g)
            for (int r = 0; r < 4; ++r) {
                float p = __expf(s[g][r] * SCALE);
                lrow[r] += p;
                Pl[wave][(quad * 4 + r) * PLP + g * 16 + lo] = f2b(p);
            }
        __syncthreads();

        short8 pf = *(const short8*)(&Pl[wave][lo * PLP + quad * 8]);
        for (int ni = 0; ni < 8; ++ni) {
            short8 vf = *(const short8*)(Vt + (ni * 16 + lo) * VTP + quad * 8);
            o[ni] = __builtin_amdgcn_mfma_f32_16x16x32_bf16(pf, vf, o[ni], 0, 0, 0);
        }
    }

    for (int r = 0; r < 4; ++r)
        for (int off = 1; off < 16; off <<= 1)
            lrow[r] += __shfl_xor(lrow[r], off, 64);

    for (int ni = 0; ni < 8; ++ni)
        for (int r = 0; r < 4; ++r) {
            int grow = pair * SEQ + q0 + wave * 16 + quad * 4 + r;
            Opart[(size_t)kz * OPART_ELEMS + (size_t)grow * HD + ni * 16 + lo] =
                f2b(o[ni][r]);
        }
    if (lo == 0)
        for (int r = 0; r < 4; ++r) {
            int grow = pair * SEQ + q0 + wave * 16 + quad * 4 + r;
            lsum[kz * ROWS_P + grow] = lrow[r];
        }
}

// ---------------------------------------------------------------------------
// Local heads (h=6..9), banded-flash MFMA.  (unchanged)
// ---------------------------------------------------------------------------
__global__ __launch_bounds__(256) void attn_local_mfma(
    const short* __restrict__ qkv, short* __restrict__ att)
{
    const int pair = blockIdx.y;          // 0..7
    const int b    = pair >> 2;
    const int h    = 6 + (pair & 3);
    const int q0   = blockIdx.x * 64;
    const int t    = threadIdx.x;
    const int wave = t >> 6;
    const int lane = t & 63;
    const int quad = lane >> 4;
    const int lo   = lane & 15;

    __shared__ short Ks[32 * KSP];
    __shared__ short Vr[32 * KSP];
    __shared__ short Vt[128 * VTP];
    __shared__ short Pl[4][16 * PLP];

    const short* base = qkv + (size_t)b * SEQ * QKVROW;

    short8 qf[4];
    {
        int qrow = q0 + wave * 16 + lo;
        const short* qp = base + (size_t)qrow * QKVROW + h * HD;
        for (int c = 0; c < 4; ++c)
            qf[c] = *(const short8*)(qp + c * 32 + quad * 8);
    }

    f32x4 o[8];
    for (int i = 0; i < 8; ++i) o[i] = (f32x4){0.f, 0.f, 0.f, 0.f};
    float lrow[4] = {0.f, 0.f, 0.f, 0.f};

    const int skey = t >> 3;
    const int sdc  = (t & 7) * 16;
    const int thd  = t & 127;
    const int tkc  = (t >> 7) * 16;
    const int irow = q0 + wave * 16 + quad * 4;   // query row = irow + r

    const int ks = max(0, q0 - 32);
    const int ke = min(SEQ, q0 + 96);
    for (int k0 = ks; k0 < ke; k0 += 32) {
        {
            const short* kro = base + (size_t)(k0 + skey) * QKVROW + DMODEL     + h * HD + sdc;
            const short* vro = base + (size_t)(k0 + skey) * QKVROW + 2 * DMODEL + h * HD + sdc;
            short8 ka = *(const short8*)kro;
            short8 kb = *(const short8*)(kro + 8);
            short8 va = *(const short8*)vro;
            short8 vb = *(const short8*)(vro + 8);
            *(short8*)(Ks + skey * KSP + sdc)     = ka;
            *(short8*)(Ks + skey * KSP + sdc + 8) = kb;
            *(short8*)(Vr + skey * KSP + sdc)     = va;
            *(short8*)(Vr + skey * KSP + sdc + 8) = vb;
        }
        __syncthreads();   // B1

        {
            short8 x0, x1;
            for (int j = 0; j < 8; ++j) x0[j] = Vr[(tkc + j) * KSP + thd];
            for (int j = 0; j < 8; ++j) x1[j] = Vr[(tkc + 8 + j) * KSP + thd];
            *(short8*)(Vt + thd * VTP + tkc)     = x0;
            *(short8*)(Vt + thd * VTP + tkc + 8) = x1;
        }

        f32x4 s[2];
        s[0] = (f32x4){0.f, 0.f, 0.f, 0.f};
        s[1] = (f32x4){0.f, 0.f, 0.f, 0.f};
        for (int g = 0; g < 2; ++g)
            for (int c = 0; c < 4; ++c) {
                short8 kf = *(const short8*)(Ks + (g * 16 + lo) * KSP + c * 32 + quad * 8);
                s[g] = __builtin_amdgcn_mfma_f32_16x16x32_bf16(qf[c], kf, s[g], 0, 0, 0);
            }

        // mask |i-j|<=32, p=exp(s*scale) else 0
        for (int g = 0; g < 2; ++g)
            for (int r = 0; r < 4; ++r) {
                int j = k0 + g * 16 + lo;
                int d = irow + r - j;
                float p = (d >= -32 && d <= 32) ? __expf(s[g][r] * SCALE) : 0.f;
                lrow[r] += p;
                Pl[wave][(quad * 4 + r) * PLP + g * 16 + lo] = f2b(p);
            }
        __syncthreads();   // B2

        short8 pf = *(const short8*)(&Pl[wave][lo * PLP + quad * 8]);
        for (int ni = 0; ni < 8; ++ni) {
            short8 vf = *(const short8*)(Vt + (ni * 16 + lo) * VTP + quad * 8);
            o[ni] = __builtin_amdgcn_mfma_f32_16x16x32_bf16(pf, vf, o[ni], 0, 0, 0);
        }
    }

    for (int r = 0; r < 4; ++r)
        for (int off = 1; off < 16; off <<= 1)
            lrow[r] += __shfl_xor(lrow[r], off, 64);

    for (int ni = 0; ni < 8; ++ni)
        for (int r = 0; r < 4; ++r) {
            int row = irow + r;
            size_t off = ((size_t)(b * SEQ + row)) * DMODEL + h * HD + ni * 16 + lo;
            att[off] = f2b(o[ni][r] / lrow[r]);
        }
}

// ---------------------------------------------------------------------------
// Fused post-attention: merge (heads 0-5) + global (10-11).  (unchanged)
// ---------------------------------------------------------------------------
#define MERGE_BLOCKS  12288   // NPAIR*SEQ*HD/256
#define GLOBAL_BLOCKS 2048    // (SEQ/4)*4

__global__ __launch_bounds__(256) void postattn_k(
    const short* __restrict__ qkv, const short* __restrict__ Opart,
    const float* __restrict__ lsum, short* __restrict__ att)
{
    const int bid  = blockIdx.x;
    const int t    = threadIdx.x;
    const int wave = t >> 6;
    const int lane = t & 63;

    if (bid < MERGE_BLOCKS) {
        int idx  = bid * 256 + t;
        int pair = idx >> 18;
        int q    = (idx >> 7) & (SEQ - 1);
        int hd   = idx & (HD - 1);
        int row  = pair * SEQ + q;
        float osum = 0.f, ls = 0.f;
        for (int z = 0; z < NSPLIT; ++z) {
            ls   += lsum[z * ROWS_P + row];
            osum += b2f(Opart[(size_t)z * OPART_ELEMS + (size_t)row * HD + hd]);
        }
        int b = pair / 6, h = pair % 6;
        att[((size_t)(b * SEQ + q)) * DMODEL + h * HD + hd] = f2b(osum / ls);
    } else {
        int gb   = bid - MERGE_BLOCKS;
        int pair = gb >> 9;               // 0..3
        int q    = (gb & 511) * 4 + wave;
        int b    = pair >> 1;
        int h    = 10 + (pair & 1);

        const short* base = qkv + (size_t)b * SEQ * QKVROW;
        const short* qp   = base + (size_t)q * QKVROW + h * HD;
        const short* k0   = base + DMODEL + h * HD;
        const short* k1   = base + (size_t)(SEQ - 1) * QKVROW + DMODEL + h * HD;

        float s0 = fmaf(b2f(qp[lane]), b2f(k0[lane]),
                   b2f(qp[lane + 64]) * b2f(k0[lane + 64]));
        float s1 = fmaf(b2f(qp[lane]), b2f(k1[lane]),
                   b2f(qp[lane + 64]) * b2f(k1[lane + 64]));
        for (int off = 1; off < 64; off <<= 1) {
            s0 += __shfl_xor(s0, off, 64);
            s1 += __shfl_xor(s1, off, 64);
        }
        s0 *= SCALE; s1 *= SCALE;
        float m  = fmaxf(s0, s1);
        float e0 = __expf(s0 - m), e1 = __expf(s1 - m);
        float inv = 1.f / (e0 + e1);
        float p0 = e0 * inv, p1 = e1 * inv;

        const short* v0 = base + 2 * DMODEL + h * HD;
        const short* v1 = base + (size_t)(SEQ - 1) * QKVROW + 2 * DMODEL + h * HD;
        size_t ob = ((size_t)(b * SEQ + q)) * DMODEL + h * HD;
        att[ob + lane]      = f2b(fmaf(p0, b2f(v0[lane]),      p1 * b2f(v1[lane])));
        att[ob + lane + 64] = f2b(fmaf(p0, b2f(v0[lane + 64]), p1 * b2f(v1[lane + 64])));
    }
}

// ---------------------------------------------------------------------------
extern "C" void kernel_launch(void* const* d_in, const int* in_sizes, int n_in,
                              void* d_out, int out_size, void* d_ws, size_t ws_size,
                              hipStream_t stream) {
    const float* x    = (const float*)d_in[0];
    const float* Wqkv = (const float*)d_in[1];
    const float* bqkv = (const float*)d_in[2];
    const float* Wout = (const float*)d_in[3];
    const float* bout = (const float*)d_in[4];

    // ws layout (~94.8 MB): att aliases xb (xb dead after GEMM1).
    char* p = (char*)d_ws;
    short* qkv   = (short*)p;  p += (size_t)TOK * QKVROW * 2;      // 37.75 MB
    short* Opart = (short*)p;  p += OPART_ELEMS * NSPLIT * 2;      // 25.17 MB
    float* lsum  = (float*)p;  p += (size_t)ROWS_P * NSPLIT * 4;   // 0.39 MB
    short* xb    = (short*)p;  p += (size_t)TOK * DMODEL * 2;      // 12.58 MB
    short* att   = xb;                                             // alias
    short* WqkvT = (short*)p;  p += (size_t)QKVROW * DMODEL * 2;   // 14.16 MB
    short* WoutT = (short*)p;                                      // 4.72 MB

    // 0) fused prepass
    prepass_k<<<dim3(CVT_BLOCKS + TQKV_BLOCKS + TOUT_BLOCKS), 256, 0, stream>>>(
        x, Wqkv, Wout, xb, WqkvT, WoutT);
    // 1) QKV = x @ Wqkv + bqkv (bf16 out): 128x256 4-slot pipelined, 576 blocks
    gemm_p4<true, 32, 18><<<dim3(32 * 18), 512, 0, stream>>>(
        xb, WqkvT, bqkv, (void*)qkv, QKVROW, DMODEL);
    // 2) attention: full split-K + banded local MFMA + fused merge/global
    attn_full_split<<<dim3(SEQ / 64, NPAIR, NSPLIT), 256, 0, stream>>>(qkv, Opart, lsum);
    attn_local_mfma<<<dim3(SEQ / 64, 8), 256, 0, stream>>>(qkv, att);
    postattn_k<<<dim3(MERGE_BLOCKS + GLOBAL_BLOCKS), 256, 0, stream>>>(
        qkv, Opart, lsum, att);
    // 3) out = att @ Wout + bout (fp32 out): 128x256 4-slot pipelined, 192 blocks
    gemm_p4<false, 32, 6><<<dim3(32 * 6), 512, 0, stream>>>(
        att, WoutT, bout, d_out, DMODEL, DMODEL);
}

// Round 8
// 294.054 us; speedup vs baseline: 1.3378x; 1.1464x over previous
//
#include <hip/hip_runtime.h>
#include <hip/hip_bf16.h>

// Problem constants (B=2, S=2048, DIM=1536, 12 heads x hd=128)
// Inputs fp32; OUTPUT fp32. Workspace ~94.8 MB (see kernel_launch).
#define SEQ    2048
#define TOK    4096          // B*S
#define DMODEL 1536
#define QKVROW 4608          // 3*DMODEL
#define HD     128
#define SCALE  0.08838834764831845f  // 1/sqrt(128)

#define NSPLIT 4
#define KRANGE (SEQ / NSPLIT)
#define NPAIR  12
#define ROWS_P (NPAIR * SEQ)
#define OPART_ELEMS ((size_t)ROWS_P * HD)

typedef __attribute__((ext_vector_type(8))) short short8;
typedef __attribute__((ext_vector_type(4))) short short4v;
typedef __attribute__((ext_vector_type(4))) float f32x4;

__device__ __forceinline__ float b2f(short s) {
    union { unsigned u; float f; } x;
    x.u = ((unsigned)(unsigned short)s) << 16;
    return x.f;
}
__device__ __forceinline__ short f2b(float f) {
    union { float f; unsigned u; } x; x.f = f;
    unsigned u = x.u;
    unsigned r = (u + 0x7fffu + ((u >> 16) & 1u)) >> 16;  // RNE
    return (short)r;
}

// async 16B global->LDS (m97 pattern). LDS dest: wave-uniform base + lane*16.
__device__ __forceinline__ void gld_lds16(const short* g, short* l) {
    __builtin_amdgcn_global_load_lds(
        (__attribute__((address_space(1))) void*)(g),
        (__attribute__((address_space(3))) void*)(l), 16, 0, 0);
}

// ---------------------------------------------------------------------------
// Fused prepass: x fp32->bf16, Wqkv/Wout fp32 -> transposed bf16.
// ---------------------------------------------------------------------------
#define CVT_BLOCKS  6144   // TOK*DMODEL / 1024
#define TQKV_BLOCKS 1728   // (QKVROW/64)*(DMODEL/64)
#define TOUT_BLOCKS 576    // (DMODEL/64)*(DMODEL/64)

__device__ __forceinline__ void transpose_tile(
    const float* __restrict__ W, short* __restrict__ WT,
    int K, int N, int k0, int n0, int t, short (*tile)[65])
{
    {
        int j  = t & 63;
        int i0 = (t >> 6) * 16;
        for (int ii = 0; ii < 16; ++ii)
            tile[i0 + ii][j] = f2b(W[(size_t)(k0 + i0 + ii) * N + n0 + j]);
    }
    __syncthreads();
    {
        int i  = t & 63;
        int j0 = (t >> 6) * 16;
        for (int jj = 0; jj < 16; ++jj)
            WT[(size_t)(n0 + j0 + jj) * K + k0 + i] = tile[i][j0 + jj];
    }
}

__global__ __launch_bounds__(256) void prepass_k(
    const float* __restrict__ x, const float* __restrict__ Wqkv,
    const float* __restrict__ Wout, short* __restrict__ xb,
    short* __restrict__ WqkvT, short* __restrict__ WoutT)
{
    __shared__ short tile[64][65];
    const int bid = blockIdx.x;
    const int t   = threadIdx.x;
    if (bid < CVT_BLOCKS) {
        int i = bid * 1024 + t * 4;
        float4 v = *(const float4*)(x + i);
        short4v b = { f2b(v.x), f2b(v.y), f2b(v.z), f2b(v.w) };
        *(short4v*)(xb + i) = b;
    } else if (bid < CVT_BLOCKS + TQKV_BLOCKS) {
        int tb = bid - CVT_BLOCKS;
        transpose_tile(Wqkv, WqkvT, DMODEL, QKVROW,
                       (tb / (QKVROW / 64)) * 64, (tb % (QKVROW / 64)) * 64, t, tile);
    } else {
        int tb = bid - (CVT_BLOCKS + TQKV_BLOCKS);
        transpose_tile(Wout, WoutT, DMODEL, DMODEL,
                       (tb / (DMODEL / 64)) * 64, (tb % (DMODEL / 64)) * 64, t, tile);
    }
}

// ---------------------------------------------------------------------------
// GEMM (r0 verbatim, m97 structure): C[M,N] = A[M,K] @ BT[N,K]^T + bias[N].
// Measured 112 us for GEMM1 -- at the m97-structure ceiling for this shape.
// ---------------------------------------------------------------------------
template <bool OUT_BF16>
__global__ __launch_bounds__(256) void gemm_tn_k(
    const short* __restrict__ A, const short* __restrict__ BT,
    const float* __restrict__ bias, void* __restrict__ Cout,
    int M, int N, int K)
{
    __shared__ short As[128 * 32];
    __shared__ short Bs[128 * 32];

    const int t    = threadIdx.x;
    const int wave = t >> 6;
    const int lane = t & 63;
    const int quad = lane >> 4;
    const int lo   = lane & 15;
    const int m0   = blockIdx.y * 128;
    const int n0   = blockIdx.x * 128;
    const int wm   = (wave >> 1) * 64;
    const int wn   = (wave & 1) * 64;

    const int srow = wave * 16 + (lane >> 2);
    const int scol = (lane & 3) * 8;

    const short* aP0 = A  + (size_t)(m0 + srow) * K + scol;
    const short* aP1 = A  + (size_t)(m0 + 64 + srow) * K + scol;
    const short* bP0 = BT + (size_t)(n0 + srow) * K + scol;
    const short* bP1 = BT + (size_t)(n0 + 64 + srow) * K + scol;
    short* asD0 = As + (wave * 16) * 32;
    short* asD1 = As + (64 + wave * 16) * 32;
    short* bsD0 = Bs + (wave * 16) * 32;
    short* bsD1 = Bs + (64 + wave * 16) * 32;

    f32x4 acc[4][4];
    for (int i = 0; i < 4; ++i)
        for (int j = 0; j < 4; ++j)
            acc[i][j] = (f32x4){0.f, 0.f, 0.f, 0.f};

    for (int kt = 0; kt < K; kt += 32) {
        gld_lds16(aP0 + kt, asD0);
        gld_lds16(aP1 + kt, asD1);
        gld_lds16(bP0 + kt, bsD0);
        gld_lds16(bP1 + kt, bsD1);
        __syncthreads();

        short8 af[4], bfv[4];
        for (int i = 0; i < 4; ++i) {
            af[i]  = *(const short8*)(As + (wm + i * 16 + lo) * 32 + quad * 8);
            bfv[i] = *(const short8*)(Bs + (wn + i * 16 + lo) * 32 + quad * 8);
        }
        for (int mi = 0; mi < 4; ++mi)
            for (int ni = 0; ni < 4; ++ni)
                acc[mi][ni] = __builtin_amdgcn_mfma_f32_16x16x32_bf16(
                    af[mi], bfv[ni], acc[mi][ni], 0, 0, 0);
        __syncthreads();
    }

    for (int ni = 0; ni < 4; ++ni) {
        int col  = n0 + wn + ni * 16 + lo;
        float bv = bias[col];
        for (int mi = 0; mi < 4; ++mi)
            for (int r = 0; r < 4; ++r) {
                int row = m0 + wm + mi * 16 + quad * 4 + r;
                float val = acc[mi][ni][r] + bv;
                if (OUT_BF16)
                    ((short*)Cout)[(size_t)row * N + col] = f2b(val);
                else
                    ((float*)Cout)[(size_t)row * N + col] = val;
            }
    }
}

// ---------------------------------------------------------------------------
// V transpose for full heads (h<6): vT[b][h][d][s] <- qkv V part.
// bf16->bf16, 64x64 tiles, coalesced both sides.  768 blocks, ~4 us.
// ---------------------------------------------------------------------------
#define VT_BLOCKS 768   // 12 bh * (32 s-tiles * 2 d-tiles)

__global__ __launch_bounds__(256) void vtrans_k(
    const short* __restrict__ qkv, short* __restrict__ vT)
{
    __shared__ short tile[64][65];
    const int bid = blockIdx.x;
    const int t   = threadIdx.x;
    const int bh  = bid >> 6;          // 0..11
    const int rem = bid & 63;
    const int st  = rem & 31, dt = rem >> 5;
    const int b   = bh / 6, h = bh % 6;
    const int s0  = st * 64, d0 = dt * 64;

    const short* src = qkv + (size_t)(b * SEQ + s0) * QKVROW + 2 * DMODEL + h * HD + d0;
    {
        int j = t & 63, i0 = (t >> 6) * 16;
        for (int ii = 0; ii < 16; ++ii)
            tile[i0 + ii][j] = src[(size_t)(i0 + ii) * QKVROW + j];
    }
    __syncthreads();
    {
        int i = t & 63, j0 = (t >> 6) * 16;
        short* dst = vT + ((size_t)(b * 6 + h) * HD + d0) * SEQ + s0;
        for (int jj = 0; jj < 16; ++jj)
            dst[(size_t)(j0 + jj) * SEQ + i] = tile[i][j0 + jj];
    }
}

// ---------------------------------------------------------------------------
// Flash attention full heads v2: QBLK=128 (4 waves x 32 q-rows via 2 groups),
// split-K x4, fixed-m=0 softmax.  K staged fragment-order via global_load_lds
// (conflict-free ds_read_b128); V read from vT -- B-fragments are contiguous
// 16B so the old per-tile scalar transpose (16 ds_read_u16/thread) is gone.
// Double-buffered K/V slots, ONE __syncthreads per k-tile (Pl is wave-private
// -> no barrier; per-wave DS ordering + compiler lgkm waits handle it).
// Frag conventions carried bit-for-bit from the r0-proven kernel.
// ---------------------------------------------------------------------------
#define KSP 136
#define VTP 44
#define PLP 40

__global__ __launch_bounds__(256, 3) void attn_full_v2(
    const short* __restrict__ qkv, const short* __restrict__ vT,
    short* __restrict__ Opart, float* __restrict__ lsum)
{
    const int pair = blockIdx.y;          // 12
    const int b    = pair / 6;
    const int h    = pair % 6;
    const int q0   = blockIdx.x * 128;    // 16 q-blocks
    const int kz   = blockIdx.z;          // 4
    const int t    = threadIdx.x;
    const int w    = t >> 6;
    const int lane = t & 63;
    const int quad = lane >> 4;
    const int lo   = lane & 15;

    // [slot][0=K,1=V][subtile][lane*8] -- fragment order, conflict-free.
    __shared__ short KV[2][2][8][512];    // 32 KB
    __shared__ short Pl[4][2][16 * PLP];  // 10 KB, wave-private

    const short* base = qkv + (size_t)b * SEQ * QKVROW;

    // Q fragments: 2 groups (u) x 4 c-slices.  qrow = q0 + w*32 + u*16 + lo.
    short8 qf[2][4];
#pragma unroll
    for (int u = 0; u < 2; ++u) {
        const short* qp = base + (size_t)(q0 + w * 32 + u * 16 + lo) * QKVROW + h * HD;
#pragma unroll
        for (int c = 0; c < 4; ++c)
            qf[u][c] = *(const short8*)(qp + c * 32 + quad * 8);
    }

    f32x4 o[2][8];
#pragma unroll
    for (int u = 0; u < 2; ++u)
#pragma unroll
        for (int i = 0; i < 8; ++i)
            o[u][i] = (f32x4){0.f, 0.f, 0.f, 0.f};
    float lrow[2][4] = {{0.f, 0.f, 0.f, 0.f}, {0.f, 0.f, 0.f, 0.f}};

    const int k0s = kz * KRANGE;
    // Per-lane staging sources (fragment-order permutation on GLOBAL side).
    // K subtile s = g*4+c: lane supplies K[k0+g*16+lo][c*32+quad*8 ..+8].
    // Wave w stages K subs {w, w+4} and V subs {w, w+4}.
    const short* kp0 = base + (size_t)(k0s + lo) * QKVROW      + DMODEL + h * HD + w * 32 + quad * 8;
    const short* kp1 = base + (size_t)(k0s + 16 + lo) * QKVROW + DMODEL + h * HD + w * 32 + quad * 8;
    const short* vbase = vT + ((size_t)(b * 6 + h) * HD) * SEQ;
    const short* vp0 = vbase + (size_t)(w * 16 + lo) * SEQ       + k0s + quad * 8;
    const short* vp1 = vbase + (size_t)((w + 4) * 16 + lo) * SEQ + k0s + quad * 8;

#define AFS_STG(SL, KT)                                                     \
    do {                                                                    \
        gld_lds16(kp0 + (size_t)(KT) * 32 * QKVROW, &KV[SL][0][w][0]);      \
        gld_lds16(kp1 + (size_t)(KT) * 32 * QKVROW, &KV[SL][0][w + 4][0]);  \
        gld_lds16(vp0 + (KT) * 32, &KV[SL][1][w][0]);                       \
        gld_lds16(vp1 + (KT) * 32, &KV[SL][1][w + 4][0]);                   \
    } while (0)

    AFS_STG(0, 0);
    __syncthreads();

    const int NT_ = KRANGE / 32;   // 16
#pragma unroll 1
    for (int kt = 0; kt < NT_; ++kt) {
        const int sl = kt & 1;
        if (kt + 1 < NT_) AFS_STG(sl ^ 1, kt + 1);

        // QK^T: both q-groups share each kf read (2x fragment reuse).
        f32x4 s[2][2];
        s[0][0] = s[0][1] = s[1][0] = s[1][1] = (f32x4){0.f, 0.f, 0.f, 0.f};
#pragma unroll
        for (int g = 0; g < 2; ++g)
#pragma unroll
            for (int c = 0; c < 4; ++c) {
                short8 kf = *(const short8*)(&KV[sl][0][g * 4 + c][lane * 8]);
                s[0][g] = __builtin_amdgcn_mfma_f32_16x16x32_bf16(qf[0][c], kf, s[0][g], 0, 0, 0);
                s[1][g] = __builtin_amdgcn_mfma_f32_16x16x32_bf16(qf[1][c], kf, s[1][g], 0, 0, 0);
            }

        // softmax partial (fixed m=0) + P into wave-private LDS
#pragma unroll
        for (int u = 0; u < 2; ++u)
#pragma unroll
            for (int g = 0; g < 2; ++g)
#pragma unroll
                for (int r = 0; r < 4; ++r) {
                    float p = __expf(s[u][g][r] * SCALE);
                    lrow[u][r] += p;
                    Pl[w][u][(quad * 4 + r) * PLP + g * 16 + lo] = f2b(p);
                }
        short8 pf0 = *(const short8*)(&Pl[w][0][lo * PLP + quad * 8]);
        short8 pf1 = *(const short8*)(&Pl[w][1][lo * PLP + quad * 8]);

        // PV: vf fragments straight from vT-staged LDS (no transpose).
#pragma unroll
        for (int ni = 0; ni < 8; ++ni) {
            short8 vf = *(const short8*)(&KV[sl][1][ni][lane * 8]);
            o[0][ni] = __builtin_amdgcn_mfma_f32_16x16x32_bf16(pf0, vf, o[0][ni], 0, 0, 0);
            o[1][ni] = __builtin_amdgcn_mfma_f32_16x16x32_bf16(pf1, vf, o[1][ni], 0, 0, 0);
        }
        __syncthreads();
    }
#undef AFS_STG

    for (int u = 0; u < 2; ++u)
        for (int r = 0; r < 4; ++r)
            for (int off = 1; off < 16; off <<= 1)
                lrow[u][r] += __shfl_xor(lrow[u][r], off, 64);

#pragma unroll
    for (int u = 0; u < 2; ++u)
        for (int ni = 0; ni < 8; ++ni)
            for (int r = 0; r < 4; ++r) {
                int grow = pair * SEQ + q0 + w * 32 + u * 16 + quad * 4 + r;
                Opart[(size_t)kz * OPART_ELEMS + (size_t)grow * HD + ni * 16 + lo] =
                    f2b(o[u][ni][r]);
            }
    if (lo == 0)
        for (int u = 0; u < 2; ++u)
            for (int r = 0; r < 4; ++r) {
                int grow = pair * SEQ + q0 + w * 32 + u * 16 + quad * 4 + r;
                lsum[kz * ROWS_P + grow] = lrow[u][r];
            }
}

// ---------------------------------------------------------------------------
// Local heads (h=6..9), banded-flash MFMA.  (r0 verbatim; tiny -- 4 tiles.)
// ---------------------------------------------------------------------------
__global__ __launch_bounds__(256) void attn_local_mfma(
    const short* __restrict__ qkv, short* __restrict__ att)
{
    const int pair = blockIdx.y;          // 0..7
    const int b    = pair >> 2;
    const int h    = 6 + (pair & 3);
    const int q0   = blockIdx.x * 64;
    const int t    = threadIdx.x;
    const int wave = t >> 6;
    const int lane = t & 63;
    const int quad = lane >> 4;
    const int lo   = lane & 15;

    __shared__ short Ks[32 * KSP];
    __shared__ short Vr[32 * KSP];
    __shared__ short Vt[128 * VTP];
    __shared__ short Pl[4][16 * PLP];

    const short* base = qkv + (size_t)b * SEQ * QKVROW;

    short8 qf[4];
    {
        int qrow = q0 + wave * 16 + lo;
        const short* qp = base + (size_t)qrow * QKVROW + h * HD;
        for (int c = 0; c < 4; ++c)
            qf[c] = *(const short8*)(qp + c * 32 + quad * 8);
    }

    f32x4 o[8];
    for (int i = 0; i < 8; ++i) o[i] = (f32x4){0.f, 0.f, 0.f, 0.f};
    float lrow[4] = {0.f, 0.f, 0.f, 0.f};

    const int skey = t >> 3;
    const int sdc  = (t & 7) * 16;
    const int thd  = t & 127;
    const int tkc  = (t >> 7) * 16;
    const int irow = q0 + wave * 16 + quad * 4;   // query row = irow + r

    const int ks = max(0, q0 - 32);
    const int ke = min(SEQ, q0 + 96);
    for (int k0 = ks; k0 < ke; k0 += 32) {
        {
            const short* kro = base + (size_t)(k0 + skey) * QKVROW + DMODEL     + h * HD + sdc;
            const short* vro = base + (size_t)(k0 + skey) * QKVROW + 2 * DMODEL + h * HD + sdc;
            short8 ka = *(const short8*)kro;
            short8 kb = *(const short8*)(kro + 8);
            short8 va = *(const short8*)vro;
            short8 vb = *(const short8*)(vro + 8);
            *(short8*)(Ks + skey * KSP + sdc)     = ka;
            *(short8*)(Ks + skey * KSP + sdc + 8) = kb;
            *(short8*)(Vr + skey * KSP + sdc)     = va;
            *(short8*)(Vr + skey * KSP + sdc + 8) = vb;
        }
        __syncthreads();   // B1

        {
            short8 x0, x1;
            for (int j = 0; j < 8; ++j) x0[j] = Vr[(tkc + j) * KSP + thd];
            for (int j = 0; j < 8; ++j) x1[j] = Vr[(tkc + 8 + j) * KSP + thd];
            *(short8*)(Vt + thd * VTP + tkc)     = x0;
            *(short8*)(Vt + thd * VTP + tkc + 8) = x1;
        }

        f32x4 s[2];
        s[0] = (f32x4){0.f, 0.f, 0.f, 0.f};
        s[1] = (f32x4){0.f, 0.f, 0.f, 0.f};
        for (int g = 0; g < 2; ++g)
            for (int c = 0; c < 4; ++c) {
                short8 kf = *(const short8*)(Ks + (g * 16 + lo) * KSP + c * 32 + quad * 8);
                s[g] = __builtin_amdgcn_mfma_f32_16x16x32_bf16(qf[c], kf, s[g], 0, 0, 0);
            }

        // mask |i-j|<=32, p=exp(s*scale) else 0
        for (int g = 0; g < 2; ++g)
            for (int r = 0; r < 4; ++r) {
                int j = k0 + g * 16 + lo;
                int d = irow + r - j;
                float p = (d >= -32 && d <= 32) ? __expf(s[g][r] * SCALE) : 0.f;
                lrow[r] += p;
                Pl[wave][(quad * 4 + r) * PLP + g * 16 + lo] = f2b(p);
            }
        __syncthreads();   // B2

        short8 pf = *(const short8*)(&Pl[wave][lo * PLP + quad * 8]);
        for (int ni = 0; ni < 8; ++ni) {
            short8 vf = *(const short8*)(Vt + (ni * 16 + lo) * VTP + quad * 8);
            o[ni] = __builtin_amdgcn_mfma_f32_16x16x32_bf16(pf, vf, o[ni], 0, 0, 0);
        }
    }

    for (int r = 0; r < 4; ++r)
        for (int off = 1; off < 16; off <<= 1)
            lrow[r] += __shfl_xor(lrow[r], off, 64);

    for (int ni = 0; ni < 8; ++ni)
        for (int r = 0; r < 4; ++r) {
            int row = irow + r;
            size_t off = ((size_t)(b * SEQ + row)) * DMODEL + h * HD + ni * 16 + lo;
            att[off] = f2b(o[ni][r] / lrow[r]);
        }
}

// ---------------------------------------------------------------------------
// Fused post-attention: merge (heads 0-5) + global (10-11).  (unchanged)
// ---------------------------------------------------------------------------
#define MERGE_BLOCKS  12288   // NPAIR*SEQ*HD/256
#define GLOBAL_BLOCKS 2048    // (SEQ/4)*4

__global__ __launch_bounds__(256) void postattn_k(
    const short* __restrict__ qkv, const short* __restrict__ Opart,
    const float* __restrict__ lsum, short* __restrict__ att)
{
    const int bid  = blockIdx.x;
    const int t    = threadIdx.x;
    const int wave = t >> 6;
    const int lane = t & 63;

    if (bid < MERGE_BLOCKS) {
        int idx  = bid * 256 + t;
        int pair = idx >> 18;
        int q    = (idx >> 7) & (SEQ - 1);
        int hd   = idx & (HD - 1);
        int row  = pair * SEQ + q;
        float osum = 0.f, ls = 0.f;
        for (int z = 0; z < NSPLIT; ++z) {
            ls   += lsum[z * ROWS_P + row];
            osum += b2f(Opart[(size_t)z * OPART_ELEMS + (size_t)row * HD + hd]);
        }
        int b = pair / 6, h = pair % 6;
        att[((size_t)(b * SEQ + q)) * DMODEL + h * HD + hd] = f2b(osum / ls);
    } else {
        int gb   = bid - MERGE_BLOCKS;
        int pair = gb >> 9;               // 0..3
        int q    = (gb & 511) * 4 + wave;
        int b    = pair >> 1;
        int h    = 10 + (pair & 1);

        const short* base = qkv + (size_t)b * SEQ * QKVROW;
        const short* qp   = base + (size_t)q * QKVROW + h * HD;
        const short* k0   = base + DMODEL + h * HD;
        const short* k1   = base + (size_t)(SEQ - 1) * QKVROW + DMODEL + h * HD;

        float s0 = fmaf(b2f(qp[lane]), b2f(k0[lane]),
                   b2f(qp[lane + 64]) * b2f(k0[lane + 64]));
        float s1 = fmaf(b2f(qp[lane]), b2f(k1[lane]),
                   b2f(qp[lane + 64]) * b2f(k1[lane + 64]));
        for (int off = 1; off < 64; off <<= 1) {
            s0 += __shfl_xor(s0, off, 64);
            s1 += __shfl_xor(s1, off, 64);
        }
        s0 *= SCALE; s1 *= SCALE;
        float m  = fmaxf(s0, s1);
        float e0 = __expf(s0 - m), e1 = __expf(s1 - m);
        float inv = 1.f / (e0 + e1);
        float p0 = e0 * inv, p1 = e1 * inv;

        const short* v0 = base + 2 * DMODEL + h * HD;
        const short* v1 = base + (size_t)(SEQ - 1) * QKVROW + 2 * DMODEL + h * HD;
        size_t ob = ((size_t)(b * SEQ + q)) * DMODEL + h * HD;
        att[ob + lane]      = f2b(fmaf(p0, b2f(v0[lane]),      p1 * b2f(v1[lane])));
        att[ob + lane + 64] = f2b(fmaf(p0, b2f(v0[lane + 64]), p1 * b2f(v1[lane + 64])));
    }
}

// ---------------------------------------------------------------------------
extern "C" void kernel_launch(void* const* d_in, const int* in_sizes, int n_in,
                              void* d_out, int out_size, void* d_ws, size_t ws_size,
                              hipStream_t stream) {
    const float* x    = (const float*)d_in[0];
    const float* Wqkv = (const float*)d_in[1];
    const float* bqkv = (const float*)d_in[2];
    const float* Wout = (const float*)d_in[3];
    const float* bout = (const float*)d_in[4];

    // ws layout (~94.8 MB): att aliases xb (xb dead after GEMM1);
    // vT (6.3 MB, V^T of full heads) aliases WqkvT (dead after GEMM1).
    char* p = (char*)d_ws;
    short* qkv   = (short*)p;  p += (size_t)TOK * QKVROW * 2;      // 37.75 MB
    short* Opart = (short*)p;  p += OPART_ELEMS * NSPLIT * 2;      // 25.17 MB
    float* lsum  = (float*)p;  p += (size_t)ROWS_P * NSPLIT * 4;   // 0.39 MB
    short* xb    = (short*)p;  p += (size_t)TOK * DMODEL * 2;      // 12.58 MB
    short* att   = xb;                                             // alias
    short* WqkvT = (short*)p;  p += (size_t)QKVROW * DMODEL * 2;   // 14.16 MB
    short* vT    = WqkvT;                                          // alias (6.29 MB used)
    short* WoutT = (short*)p;                                      // 4.72 MB

    // 0) fused prepass
    prepass_k<<<dim3(CVT_BLOCKS + TQKV_BLOCKS + TOUT_BLOCKS), 256, 0, stream>>>(
        x, Wqkv, Wout, xb, WqkvT, WoutT);
    // 1) QKV = x @ Wqkv + bqkv   (bf16 out, r0 GEMM)
    gemm_tn_k<true><<<dim3(QKVROW / 128, TOK / 128), 256, 0, stream>>>(
        xb, WqkvT, bqkv, (void*)qkv, TOK, QKVROW, DMODEL);
    // 2) V^T for full heads (WqkvT now dead -> reuse as vT)
    vtrans_k<<<dim3(VT_BLOCKS), 256, 0, stream>>>(qkv, vT);
    // 3) attention: full v2 (QBLK=128, gld_lds staging, no scalar transpose)
    attn_full_v2<<<dim3(SEQ / 128, NPAIR, NSPLIT), 256, 0, stream>>>(
        qkv, vT, Opart, lsum);
    attn_local_mfma<<<dim3(SEQ / 64, 8), 256, 0, stream>>>(qkv, att);
    postattn_k<<<dim3(MERGE_BLOCKS + GLOBAL_BLOCKS), 256, 0, stream>>>(
        qkv, Opart, lsum, att);
    // 4) out = att @ Wout + bout  (fp32 out, r0 GEMM)
    gemm_tn_k<false><<<dim3(DMODEL / 128, TOK / 128), 256, 0, stream>>>(
        att, WoutT, bout, d_out, TOK, DMODEL, DMODEL);
}